// Round 8
// baseline (239.677 us; speedup 1.0000x reference)
//
#include <hip/hip_runtime.h>
#include <hip/hip_fp16.h>
#include <cstdint>
#include <cstddef>

#define BB 16
#define LL 2048
#define CC 512   // H*E
#define TK 7     // int(log(2048)) = 7
#define PDC(a) ((a) + ((a) >> 4))   // cf-unit LDS pad: +1 cf per 16

typedef float2 cf;

__device__ inline cf cadd(cf a, cf b){ return make_float2(a.x + b.x, a.y + b.y); }
__device__ inline cf csub(cf a, cf b){ return make_float2(a.x - b.x, a.y - b.y); }
__device__ inline cf cmul(cf a, cf b){ return make_float2(a.x*b.x - a.y*b.y, a.x*b.y + a.y*b.x); }

// S*i*z : forward S=-1 -> (z.y, -z.x); inverse S=+1 -> (-z.y, z.x)
template<int S> __device__ inline cf crot(cf z){
  return (S < 0) ? make_float2(z.y, -z.x) : make_float2(-z.y, z.x);
}

template<int S> __device__ inline void dft4(cf* x){
  const cf t0 = cadd(x[0], x[2]), t1 = csub(x[0], x[2]);
  const cf t2 = cadd(x[1], x[3]), t3 = csub(x[1], x[3]);
  const cf r = crot<S>(t3);
  x[0] = cadd(t0, t2); x[2] = csub(t0, t2);
  x[1] = cadd(t1, r);  x[3] = csub(t1, r);
}

template<int S> __device__ inline void dft8(cf* x){
  cf e[4] = { x[0], x[2], x[4], x[6] };
  cf o[4] = { x[1], x[3], x[5], x[7] };
  dft4<S>(e); dft4<S>(o);
  const float H = 0.70710678118654752440f;
  o[1] = cmul(o[1], make_float2(H, (float)S * H));
  o[2] = crot<S>(o[2]);
  o[3] = cmul(o[3], make_float2(-H, (float)S * H));
  x[0] = cadd(e[0], o[0]); x[4] = csub(e[0], o[0]);
  x[1] = cadd(e[1], o[1]); x[5] = csub(e[1], o[1]);
  x[2] = cadd(e[2], o[2]); x[6] = csub(e[2], o[2]);
  x[3] = cadd(e[3], o[3]); x[7] = csub(e[3], o[3]);
}

struct Tw { cf w2[7], w3[7], w4a[3], w4b[3]; };

template<int S>
__device__ inline void make_tw(int tid, Tw& T){
  const float base = (float)S * 6.283185307179586f / 2048.0f;
  const int j7 = tid & 7, j63 = tid & 63;
#pragma unroll
  for (int i = 0; i < 7; ++i){
    float s, c;
    __sincosf(base * (float)(32 * (i + 1) * j7), &s, &c);  T.w2[i] = make_float2(c, s);
    __sincosf(base * (float)( 4 * (i + 1) * j63), &s, &c); T.w3[i] = make_float2(c, s);
  }
#pragma unroll
  for (int i = 0; i < 3; ++i){
    float s, c;
    __sincosf(base * (float)((i + 1) * tid), &s, &c);         T.w4a[i] = make_float2(c, s);
    __sincosf(base * (float)((i + 1) * (tid + 256)), &s, &c); T.w4b[i] = make_float2(c, s);
  }
}

// Full 2048-pt Stockham FFT (radix 8-8-8-4), cf-interleaved LDS (b64 ops).
// Input: x[8] registers (x[t] = sample tid + 256t). Output: Z in Cc[PDC(f)].
// Leaves a trailing sync after stage-4 writes.
template<int S>
__device__ inline void fft2048(cf* x, cf* Bc, cf* Cc, const Tw& T, int tid){
  // stage 1: radix-8, Ls=1 (no twiddles)
  dft8<S>(x);
#pragma unroll
  for (int t = 0; t < 8; ++t) Bc[PDC((tid << 3) + t)] = x[t];
  __syncthreads();
  { // stage 2: radix-8, Ls=8
    cf y[8];
#pragma unroll
    for (int t = 0; t < 8; ++t) y[t] = Bc[PDC(tid + (t << 8))];
#pragma unroll
    for (int t = 1; t < 8; ++t) y[t] = cmul(y[t], T.w2[t - 1]);
    dft8<S>(y);
    const int base = ((tid >> 3) << 6) + (tid & 7);
#pragma unroll
    for (int t = 0; t < 8; ++t) Cc[PDC(base + (t << 3))] = y[t];
  }
  __syncthreads();
  { // stage 3: radix-8, Ls=64
    cf y[8];
#pragma unroll
    for (int t = 0; t < 8; ++t) y[t] = Cc[PDC(tid + (t << 8))];
#pragma unroll
    for (int t = 1; t < 8; ++t) y[t] = cmul(y[t], T.w3[t - 1]);
    dft8<S>(y);
    const int base = ((tid >> 6) << 9) + (tid & 63);
#pragma unroll
    for (int t = 0; t < 8; ++t) Bc[PDC(base + (t << 6))] = y[t];
  }
  __syncthreads();
  { // stage 4: radix-4, Ls=512 (two butterflies per thread)
#pragma unroll
    for (int h = 0; h < 2; ++h){
      const int j = tid + (h << 8);
      cf y[4];
#pragma unroll
      for (int t = 0; t < 4; ++t) y[t] = Bc[PDC(j + (t << 9))];
      const cf* w = h ? T.w4b : T.w4a;
#pragma unroll
      for (int t = 1; t < 4; ++t) y[t] = cmul(y[t], w[t - 1]);
      dft4<S>(y);
#pragma unroll
      for (int t = 0; t < 4; ++t) Cc[PDC(j + (t << 9))] = y[t];
    }
  }
  __syncthreads();
}

// ---------------------------------------------------------------------------
// Fused Phase 1+2: per (b, group of 16 channels): transpose q,k rows in-kernel
// (4 rounds of 4 channels staged in LDS as half2), forward FFT of
// z_c = q_c + i*k_c, accumulate P[f] += Q_c[f]*conj(K_c[f]); write P partial.
// ---------------------------------------------------------------------------
__global__ __launch_bounds__(256) void fft_fwd_fused(const float* __restrict__ q,
                                                     const float* __restrict__ k,
                                                     float2* __restrict__ Ppart){
  int bid = blockIdx.x;
  const int g = bid & 31; const int b = bid >> 5;
  const int tid = threadIdx.x;
  __shared__ __half2 S2[2048][5];   // [t][ch], pad to 5 -> stride-5 banks (free)
  __shared__ cf Bc[2176];
  __shared__ cf Cc[2176];
  Tw T; make_tw<-1>(tid, T);
  float accRe[8] = {0,0,0,0,0,0,0,0};
  float accIm[8] = {0,0,0,0,0,0,0,0};
  const float* qb = q + (size_t)b * LL * CC + (size_t)(g << 4);
  const float* kb = k + (size_t)b * LL * CC + (size_t)(g << 4);

  float4 aq[8], ak[8];
  // prologue: round-0 loads, convert, stage
#pragma unroll
  for (int j = 0; j < 8; ++j){
    const int t = tid + (j << 8);
    aq[j] = *reinterpret_cast<const float4*>(qb + (size_t)t * CC);
    ak[j] = *reinterpret_cast<const float4*>(kb + (size_t)t * CC);
  }
#pragma unroll
  for (int j = 0; j < 8; ++j){
    const int t = tid + (j << 8);
    S2[t][0] = __floats2half2_rn(aq[j].x, ak[j].x);
    S2[t][1] = __floats2half2_rn(aq[j].y, ak[j].y);
    S2[t][2] = __floats2half2_rn(aq[j].z, ak[j].z);
    S2[t][3] = __floats2half2_rn(aq[j].w, ak[j].w);
  }

  for (int r = 0; r < 4; ++r){
    __syncthreads();   // staged data of round r visible
    if (r < 3){
      // issue next round's loads; consumed after the 4 FFTs below
#pragma unroll
      for (int j = 0; j < 8; ++j){
        const int t = tid + (j << 8);
        aq[j] = *reinterpret_cast<const float4*>(qb + (size_t)t * CC + ((r + 1) << 2));
        ak[j] = *reinterpret_cast<const float4*>(kb + (size_t)t * CC + ((r + 1) << 2));
      }
    }
#pragma unroll
    for (int ch = 0; ch < 4; ++ch){
      cf x[8];
#pragma unroll
      for (int j = 0; j < 8; ++j) x[j] = __half22float2(S2[tid + (j << 8)][ch]);
      fft2048<-1>(x, Bc, Cc, T, tid);
      // combine: Z in Cc. Re(Q conjK)=0.5*(Bi*Ar+Br*Ai), Im=0.25*(|A|^2-|B|^2)
#pragma unroll
      for (int rr = 0; rr < 8; ++rr){
        const int f = tid + (rr << 8);
        const int p = (2048 - f) & 2047;
        const cf A = Cc[PDC(f)];
        const cf Bv = Cc[PDC(p)];
        accRe[rr] += 0.5f  * (Bv.y * A.x + Bv.x * A.y);
        accIm[rr] += 0.25f * (A.x * A.x + A.y * A.y - Bv.x * Bv.x - Bv.y * Bv.y);
      }
    }
    if (r < 3){
      // all threads passed ch3's stage-1 barrier -> no one reads S2 any more
#pragma unroll
      for (int j = 0; j < 8; ++j){
        const int t = tid + (j << 8);
        S2[t][0] = __floats2half2_rn(aq[j].x, ak[j].x);
        S2[t][1] = __floats2half2_rn(aq[j].y, ak[j].y);
        S2[t][2] = __floats2half2_rn(aq[j].z, ak[j].z);
        S2[t][3] = __floats2half2_rn(aq[j].w, ak[j].w);
      }
    }
  }
  float2* pp = Ppart + (((size_t)b * 32 + g) << 11);
#pragma unroll
  for (int r = 0; r < 8; ++r)
    pp[tid + (r << 8)] = make_float2(accRe[r], accIm[r]);
}

// ---------------------------------------------------------------------------
// Phase 2b: P[b,f] = sum_g Ppart[b,g,f]   (32 partials)
// ---------------------------------------------------------------------------
__global__ __launch_bounds__(256) void reduce_P(const float2* __restrict__ Ppart,
                                                float2* __restrict__ P){
  const int gid = blockIdx.x * 256 + threadIdx.x;  // 0..32767
  const int b = gid >> 11, f = gid & 2047;
  float sr = 0.f, si = 0.f;
#pragma unroll 8
  for (int g = 0; g < 32; ++g){
    const float2 v = Ppart[(((size_t)b * 32 + g) << 11) + f];
    sr += v.x; si += v.y;
  }
  P[((size_t)b << 11) + f] = make_float2(sr, si);
}

// ---------------------------------------------------------------------------
// Phase 3: per b: inverse FFT of P, scale -> mv; fused top-7 + softmax.
// ---------------------------------------------------------------------------
__global__ __launch_bounds__(256) void fft_inv_topk(const float2* __restrict__ P,
                                                    int* __restrict__ delays,
                                                    float* __restrict__ probs){
  const int b = blockIdx.x;
  const int tid = threadIdx.x;
  __shared__ cf Bc[2176];
  __shared__ cf Cc[2176];
  __shared__ float vals[2048];
  __shared__ float rv[256]; __shared__ int ri[256];
  __shared__ float wsel[TK]; __shared__ int dsel[TK];
  Tw T; make_tw<1>(tid, T);
  cf x[8];
#pragma unroll
  for (int t = 0; t < 8; ++t) x[t] = P[((size_t)b << 11) + tid + (t << 8)];
  fft2048<1>(x, Bc, Cc, T, tid);
  const float scale = 1.0f / (2048.0f * 512.0f);
#pragma unroll
  for (int r = 0; r < 8; ++r){
    const int t = tid + (r << 8);
    vals[t] = Cc[PDC(t)].x * scale;
  }
  __syncthreads();
  for (int kk = 0; kk < TK; ++kk){
    float best = -1e30f; int bi = LL;
    for (int i = tid; i < LL; i += 256){
      const float xv = vals[i];
      if (xv > best){ best = xv; bi = i; }
    }
    rv[tid] = best; ri[tid] = bi;
    __syncthreads();
    for (int s = 128; s > 0; s >>= 1){
      if (tid < s){
        const float ov = rv[tid + s]; const int oi = ri[tid + s];
        if (ov > rv[tid] || (ov == rv[tid] && oi < ri[tid])){ rv[tid] = ov; ri[tid] = oi; }
      }
      __syncthreads();
    }
    if (tid == 0){ wsel[kk] = rv[0]; dsel[kk] = ri[0]; vals[ri[0]] = -1e30f; }
    __syncthreads();
  }
  if (tid == 0){
    const float m = wsel[0];
    float e[TK], ssum = 0.f;
#pragma unroll
    for (int i = 0; i < TK; ++i){ e[i] = expf(wsel[i] - m); ssum += e[i]; }
    const float inv = 1.0f / ssum;
#pragma unroll
    for (int i = 0; i < TK; ++i){
      probs[b * TK + i] = e[i] * inv;
      delays[b * TK + i] = dsel[i];
    }
  }
}

// ---------------------------------------------------------------------------
// Phase 4: out[b,t,:] = sum_k probs[b,k] * v[b,(t+delay[b,k])%L,:]
// ---------------------------------------------------------------------------
__global__ __launch_bounds__(256) void agg_out(const float* __restrict__ v,
                                               const int* __restrict__ delays,
                                               const float* __restrict__ probs,
                                               float* __restrict__ out){
  const int g = blockIdx.x * 256 + threadIdx.x;  // float4 index
  const int inrow = g & 127;        // CC/4 = 128
  const int row = g >> 7;           // b*L + t
  const int b = row >> 11;
  const int t = row & (LL - 1);
  float4 acc = make_float4(0.f, 0.f, 0.f, 0.f);
#pragma unroll
  for (int kk = 0; kk < TK; ++kk){
    const int d = delays[b * TK + kk];
    const float p = probs[b * TK + kk];
    const int srcr = (t + d) & (LL - 1);
    const float4 xv = reinterpret_cast<const float4*>(v)[(size_t)(b * LL + srcr) * 128 + inrow];
    acc.x += p * xv.x; acc.y += p * xv.y; acc.z += p * xv.z; acc.w += p * xv.w;
  }
  reinterpret_cast<float4*>(out)[g] = acc;
}

// ---------------------------------------------------------------------------
extern "C" void kernel_launch(void* const* d_in, const int* in_sizes, int n_in,
                              void* d_out, int out_size, void* d_ws, size_t ws_size,
                              hipStream_t stream){
  const float* q = (const float*)d_in[0];
  const float* k = (const float*)d_in[1];
  const float* v = (const float*)d_in[2];
  float* out = (float*)d_out;

  char* ws = (char*)d_ws;
  const size_t PP_BYTES = (size_t)BB * 32 * LL * sizeof(float2);    // 8.4 MB
  const size_t P_BYTES  = (size_t)BB * LL * sizeof(float2);         // 256 KB
  float2* Ppart = (float2*)ws;
  float2* Pbuf  = (float2*)(ws + PP_BYTES);
  int* delays = (int*)(ws + PP_BYTES + P_BYTES);
  float* probs = (float*)(ws + PP_BYTES + P_BYTES + 1024);

  hipLaunchKernelGGL(fft_fwd_fused, dim3(BB * 32), dim3(256), 0, stream, q, k, Ppart);
  hipLaunchKernelGGL(reduce_P, dim3((BB * LL) / 256), dim3(256), 0, stream, Ppart, Pbuf);
  hipLaunchKernelGGL(fft_inv_topk, dim3(BB), dim3(256), 0, stream, Pbuf, delays, probs);
  hipLaunchKernelGGL(agg_out, dim3((BB * LL * (CC / 4)) / 256), dim3(256), 0, stream,
                     v, delays, probs, out);
}

// Round 9
// 137.528 us; speedup vs baseline: 1.7428x; 1.7428x over previous
//
#include <hip/hip_runtime.h>
#include <hip/hip_fp16.h>
#include <cstdint>
#include <cstddef>

#define BB 16
#define LL 2048
#define CC 512   // H*E
#define TK 7     // int(log(2048)) = 7
#define PDC(a) ((a) + ((a) >> 4))   // cf-unit LDS pad: +1 cf per 16
#define PSTR 1056                   // Ppart per-group stride (1025 used)

typedef float2 cf;
typedef __attribute__((ext_vector_type(4))) float f32x4v;

__device__ inline cf cadd(cf a, cf b){ return make_float2(a.x + b.x, a.y + b.y); }
__device__ inline cf csub(cf a, cf b){ return make_float2(a.x - b.x, a.y - b.y); }
__device__ inline cf cmul(cf a, cf b){ return make_float2(a.x*b.x - a.y*b.y, a.x*b.y + a.y*b.x); }

// S*i*z : forward S=-1 -> (z.y, -z.x); inverse S=+1 -> (-z.y, z.x)
template<int S> __device__ inline cf crot(cf z){
  return (S < 0) ? make_float2(z.y, -z.x) : make_float2(-z.y, z.x);
}

template<int S> __device__ inline void dft4(cf* x){
  const cf t0 = cadd(x[0], x[2]), t1 = csub(x[0], x[2]);
  const cf t2 = cadd(x[1], x[3]), t3 = csub(x[1], x[3]);
  const cf r = crot<S>(t3);
  x[0] = cadd(t0, t2); x[2] = csub(t0, t2);
  x[1] = cadd(t1, r);  x[3] = csub(t1, r);
}

template<int S> __device__ inline void dft8(cf* x){
  cf e[4] = { x[0], x[2], x[4], x[6] };
  cf o[4] = { x[1], x[3], x[5], x[7] };
  dft4<S>(e); dft4<S>(o);
  const float H = 0.70710678118654752440f;
  o[1] = cmul(o[1], make_float2(H, (float)S * H));
  o[2] = crot<S>(o[2]);
  o[3] = cmul(o[3], make_float2(-H, (float)S * H));
  x[0] = cadd(e[0], o[0]); x[4] = csub(e[0], o[0]);
  x[1] = cadd(e[1], o[1]); x[5] = csub(e[1], o[1]);
  x[2] = cadd(e[2], o[2]); x[6] = csub(e[2], o[2]);
  x[3] = cadd(e[3], o[3]); x[7] = csub(e[3], o[3]);
}

struct Tw { cf w2[7], w3[7], w4a[3], w4b[3]; };

template<int S>
__device__ inline void make_tw(int tid, Tw& T){
  const float base = (float)S * 6.283185307179586f / 2048.0f;
  const int j7 = tid & 7, j63 = tid & 63;
#pragma unroll
  for (int i = 0; i < 7; ++i){
    float s, c;
    __sincosf(base * (float)(32 * (i + 1) * j7), &s, &c);  T.w2[i] = make_float2(c, s);
    __sincosf(base * (float)( 4 * (i + 1) * j63), &s, &c); T.w3[i] = make_float2(c, s);
  }
#pragma unroll
  for (int i = 0; i < 3; ++i){
    float s, c;
    __sincosf(base * (float)((i + 1) * tid), &s, &c);         T.w4a[i] = make_float2(c, s);
    __sincosf(base * (float)((i + 1) * (tid + 256)), &s, &c); T.w4b[i] = make_float2(c, s);
  }
}

// Full 2048-pt Stockham FFT (radix 8-8-8-4), cf-interleaved LDS (b64 ops).
// Input: x[8] registers (x[t] = sample tid + 256t). Output: Z in Cc[PDC(f)].
// Leaves a trailing sync after stage-4 writes.
template<int S>
__device__ inline void fft2048(cf* x, cf* Bc, cf* Cc, const Tw& T, int tid){
  // stage 1: radix-8, Ls=1 (no twiddles)
  dft8<S>(x);
#pragma unroll
  for (int t = 0; t < 8; ++t) Bc[PDC((tid << 3) + t)] = x[t];
  __syncthreads();
  { // stage 2: radix-8, Ls=8
    cf y[8];
#pragma unroll
    for (int t = 0; t < 8; ++t) y[t] = Bc[PDC(tid + (t << 8))];
#pragma unroll
    for (int t = 1; t < 8; ++t) y[t] = cmul(y[t], T.w2[t - 1]);
    dft8<S>(y);
    const int base = ((tid >> 3) << 6) + (tid & 7);
#pragma unroll
    for (int t = 0; t < 8; ++t) Cc[PDC(base + (t << 3))] = y[t];
  }
  __syncthreads();
  { // stage 3: radix-8, Ls=64
    cf y[8];
#pragma unroll
    for (int t = 0; t < 8; ++t) y[t] = Cc[PDC(tid + (t << 8))];
#pragma unroll
    for (int t = 1; t < 8; ++t) y[t] = cmul(y[t], T.w3[t - 1]);
    dft8<S>(y);
    const int base = ((tid >> 6) << 9) + (tid & 63);
#pragma unroll
    for (int t = 0; t < 8; ++t) Bc[PDC(base + (t << 6))] = y[t];
  }
  __syncthreads();
  { // stage 4: radix-4, Ls=512 (two butterflies per thread)
#pragma unroll
    for (int h = 0; h < 2; ++h){
      const int j = tid + (h << 8);
      cf y[4];
#pragma unroll
      for (int t = 0; t < 4; ++t) y[t] = Bc[PDC(j + (t << 9))];
      const cf* w = h ? T.w4b : T.w4a;
#pragma unroll
      for (int t = 1; t < 4; ++t) y[t] = cmul(y[t], w[t - 1]);
      dft4<S>(y);
#pragma unroll
      for (int t = 0; t < 4; ++t) Cc[PDC(j + (t << 9))] = y[t];
    }
  }
  __syncthreads();
}

// ---------------------------------------------------------------------------
// Phase 1: z[b][c][t] = half2(q[b][t][c], k[b][t][c])  (64x64 fp16 LDS tile)
// q,k are single-use streams -> nontemporal loads (keep L3 for z/Ppart).
// ---------------------------------------------------------------------------
__global__ __launch_bounds__(256) void transpose_pack(const float* __restrict__ q,
                                                      const float* __restrict__ k,
                                                      __half2* __restrict__ z){
  int bid = blockIdx.x;
  const int tt = bid & 31; bid >>= 5;
  const int ct = bid & 7;  bid >>= 3;
  const int b = bid;
  const int t0 = tt << 6, c0 = ct << 6;
  __shared__ __half2 T[64][69];   // [t][c], pad 69 to break bank strides
  const int tid = threadIdx.x;
  const size_t inbase = ((size_t)b * LL + t0) * CC + c0;
  const int c4 = (tid & 15) << 2;
  f32x4v a[4], e[4];
#pragma unroll
  for (int p2 = 0; p2 < 4; ++p2){
    const int row = (p2 << 4) + (tid >> 4);
    a[p2] = __builtin_nontemporal_load(
        reinterpret_cast<const f32x4v*>(q + inbase + (size_t)row * CC + c4));
    e[p2] = __builtin_nontemporal_load(
        reinterpret_cast<const f32x4v*>(k + inbase + (size_t)row * CC + c4));
  }
#pragma unroll
  for (int p2 = 0; p2 < 4; ++p2){
    const int row = (p2 << 4) + (tid >> 4);
    T[row][c4 + 0] = __floats2half2_rn(a[p2][0], e[p2][0]);
    T[row][c4 + 1] = __floats2half2_rn(a[p2][1], e[p2][1]);
    T[row][c4 + 2] = __floats2half2_rn(a[p2][2], e[p2][2]);
    T[row][c4 + 3] = __floats2half2_rn(a[p2][3], e[p2][3]);
  }
  __syncthreads();
  const size_t outbase = ((size_t)b * CC + c0) * LL + (size_t)t0;
#pragma unroll
  for (int it = 0; it < 4; ++it){
    const int idx = (it << 8) + tid;
    const int c = idx >> 4;                 // c_local 0..63
    const int t4 = (idx & 15) << 2;         // t_local base (x4)
    const __half2 u0 = T[t4 + 0][c], u1 = T[t4 + 1][c];
    const __half2 u2 = T[t4 + 2][c], u3 = T[t4 + 3][c];
    uint4 w;
    w.x = *reinterpret_cast<const uint*>(&u0);
    w.y = *reinterpret_cast<const uint*>(&u1);
    w.z = *reinterpret_cast<const uint*>(&u2);
    w.w = *reinterpret_cast<const uint*>(&u3);
    *reinterpret_cast<uint4*>(&z[outbase + (size_t)c * LL + t4]) = w;
  }
}

// ---------------------------------------------------------------------------
// Phase 2: per (b, group of 8 channels): forward FFT of z_c = q_c + i*k_c,
// accumulate P[f] += Q_c[f]*conj(K_c[f]) for f in [0,1024] only (Hermitian:
// P[2048-f] = conj(P[f]), reconstructed in reduce_P).
// ---------------------------------------------------------------------------
__global__ __launch_bounds__(256) void fft_fwd(const __half2* __restrict__ z,
                                               float2* __restrict__ Ppart){
  int bid = blockIdx.x;
  const int g = bid & 63; const int b = bid >> 6;
  const int tid = threadIdx.x;
  __shared__ cf Bc[2176];
  __shared__ cf Cc[2176];
  Tw T; make_tw<-1>(tid, T);
  const __half2* zg = z + (((size_t)b * CC + (size_t)g * 8) << 11);
  float accRe[4] = {0,0,0,0};
  float accIm[4] = {0,0,0,0};
  float acc1024 = 0.f;
  __half2 h[8];
#pragma unroll
  for (int t = 0; t < 8; ++t) h[t] = zg[tid + (t << 8)];
  for (int ch = 0; ch < 8; ++ch){
    cf x[8];
#pragma unroll
    for (int t = 0; t < 8; ++t) x[t] = __half22float2(h[t]);
    if (ch < 7){
      const __half2* zn = zg + ((size_t)(ch + 1) << 11);
#pragma unroll
      for (int t = 0; t < 8; ++t) h[t] = zn[tid + (t << 8)];
    }
    fft2048<-1>(x, Bc, Cc, T, tid);
    // combine for f = tid + 256r, r<4 (covers 0..1023 exactly once):
    // Re(QconjK)[f] = 0.5*(Bi*Ar + Br*Ai), Im = 0.25*(|A|^2-|B|^2), B=Z[2048-f]
#pragma unroll
    for (int r = 0; r < 4; ++r){
      const int f = tid + (r << 8);
      const int p = (2048 - f) & 2047;
      const cf A = Cc[PDC(f)];
      const cf Bv = Cc[PDC(p)];
      accRe[r] += 0.5f  * (Bv.y * A.x + Bv.x * A.y);
      accIm[r] += 0.25f * (A.x * A.x + A.y * A.y - Bv.x * Bv.x - Bv.y * Bv.y);
    }
    if (tid == 0){
      const cf A = Cc[PDC(1024)];   // self-mirror: Re = Ar*Ai, Im = 0
      acc1024 += A.x * A.y;
    }
  }
  float2* pp = Ppart + ((size_t)b * 64 + g) * PSTR;
#pragma unroll
  for (int r = 0; r < 4; ++r)
    pp[tid + (r << 8)] = make_float2(accRe[r], accIm[r]);
  if (tid == 0) pp[1024] = make_float2(acc1024, 0.f);
}

// ---------------------------------------------------------------------------
// Phase 2b: P[b,f] = sum_g Ppart[b,g,min(f,2048-f)], conj for f>1024.
// ---------------------------------------------------------------------------
__global__ __launch_bounds__(256) void reduce_P(const float2* __restrict__ Ppart,
                                                float2* __restrict__ P){
  const int gid = blockIdx.x * 256 + threadIdx.x;  // 0..32767
  const int b = gid >> 11, f = gid & 2047;
  const int src = (f <= 1024) ? f : 2048 - f;
  const float sgn = (f <= 1024) ? 1.f : -1.f;
  float sr = 0.f, si = 0.f;
#pragma unroll 8
  for (int g = 0; g < 64; ++g){
    const float2 v = Ppart[((size_t)b * 64 + g) * PSTR + src];
    sr += v.x; si += v.y;
  }
  P[((size_t)b << 11) + f] = make_float2(sr, sgn * si);
}

// ---------------------------------------------------------------------------
// Phase 3: per b: inverse FFT of P, scale -> mv; fused top-7 + softmax.
// ---------------------------------------------------------------------------
__global__ __launch_bounds__(256) void fft_inv_topk(const float2* __restrict__ P,
                                                    int* __restrict__ delays,
                                                    float* __restrict__ probs){
  const int b = blockIdx.x;
  const int tid = threadIdx.x;
  __shared__ cf Bc[2176];
  __shared__ cf Cc[2176];
  __shared__ float vals[2048];
  __shared__ float rv[256]; __shared__ int ri[256];
  __shared__ float wsel[TK]; __shared__ int dsel[TK];
  Tw T; make_tw<1>(tid, T);
  cf x[8];
#pragma unroll
  for (int t = 0; t < 8; ++t) x[t] = P[((size_t)b << 11) + tid + (t << 8)];
  fft2048<1>(x, Bc, Cc, T, tid);
  const float scale = 1.0f / (2048.0f * 512.0f);
#pragma unroll
  for (int r = 0; r < 8; ++r){
    const int t = tid + (r << 8);
    vals[t] = Cc[PDC(t)].x * scale;
  }
  __syncthreads();
  for (int kk = 0; kk < TK; ++kk){
    float best = -1e30f; int bi = LL;
    for (int i = tid; i < LL; i += 256){
      const float xv = vals[i];
      if (xv > best){ best = xv; bi = i; }
    }
    rv[tid] = best; ri[tid] = bi;
    __syncthreads();
    for (int s = 128; s > 0; s >>= 1){
      if (tid < s){
        const float ov = rv[tid + s]; const int oi = ri[tid + s];
        if (ov > rv[tid] || (ov == rv[tid] && oi < ri[tid])){ rv[tid] = ov; ri[tid] = oi; }
      }
      __syncthreads();
    }
    if (tid == 0){ wsel[kk] = rv[0]; dsel[kk] = ri[0]; vals[ri[0]] = -1e30f; }
    __syncthreads();
  }
  if (tid == 0){
    const float m = wsel[0];
    float e[TK], ssum = 0.f;
#pragma unroll
    for (int i = 0; i < TK; ++i){ e[i] = expf(wsel[i] - m); ssum += e[i]; }
    const float inv = 1.0f / ssum;
#pragma unroll
    for (int i = 0; i < TK; ++i){
      probs[b * TK + i] = e[i] * inv;
      delays[b * TK + i] = dsel[i];
    }
  }
}

// ---------------------------------------------------------------------------
// Phase 4: out[b,t,:] = sum_k probs[b,k] * v[b,(t+delay[b,k])%L,:]
// 2 float4 per thread; nontemporal stores (out never re-read).
// ---------------------------------------------------------------------------
__global__ __launch_bounds__(256) void agg_out(const float* __restrict__ v,
                                               const int* __restrict__ delays,
                                               const float* __restrict__ probs,
                                               float* __restrict__ out){
  const int gid = blockIdx.x * 256 + threadIdx.x;  // pair index
  const int i0 = gid & 63;          // first float4 slot (second = i0+64)
  const int row = gid >> 6;         // b*L + t
  const int b = row >> 11;
  const int t = row & (LL - 1);
  f32x4v acc0 = {0.f, 0.f, 0.f, 0.f};
  f32x4v acc1 = {0.f, 0.f, 0.f, 0.f};
#pragma unroll
  for (int kk = 0; kk < TK; ++kk){
    const int d = delays[b * TK + kk];
    const float p = probs[b * TK + kk];
    const int srcr = (t + d) & (LL - 1);
    const size_t base = (size_t)(b * LL + srcr) * 128;
    const f32x4v x0 = reinterpret_cast<const f32x4v*>(v)[base + i0];
    const f32x4v x1 = reinterpret_cast<const f32x4v*>(v)[base + i0 + 64];
    acc0 += x0 * p;
    acc1 += x1 * p;
  }
  f32x4v* o = reinterpret_cast<f32x4v*>(out) + (size_t)row * 128;
  __builtin_nontemporal_store(acc0, o + i0);
  __builtin_nontemporal_store(acc1, o + i0 + 64);
}

// ---------------------------------------------------------------------------
extern "C" void kernel_launch(void* const* d_in, const int* in_sizes, int n_in,
                              void* d_out, int out_size, void* d_ws, size_t ws_size,
                              hipStream_t stream){
  const float* q = (const float*)d_in[0];
  const float* k = (const float*)d_in[1];
  const float* v = (const float*)d_in[2];
  float* out = (float*)d_out;

  char* ws = (char*)d_ws;
  const size_t Z_BYTES  = (size_t)BB * CC * LL * sizeof(__half2);   // 67.1 MB
  const size_t PP_BYTES = (size_t)BB * 64 * PSTR * sizeof(float2);  // 8.65 MB
  const size_t P_BYTES  = (size_t)BB * LL * sizeof(float2);         // 256 KB
  __half2* zbuf = (__half2*)ws;
  float2* Ppart = (float2*)(ws + Z_BYTES);
  float2* Pbuf  = (float2*)(ws + Z_BYTES + PP_BYTES);
  int* delays = (int*)(ws + Z_BYTES + PP_BYTES + P_BYTES);
  float* probs = (float*)(ws + Z_BYTES + PP_BYTES + P_BYTES + 1024);

  hipLaunchKernelGGL(transpose_pack, dim3(BB * 32 * 8), dim3(256), 0, stream, q, k, zbuf);
  hipLaunchKernelGGL(fft_fwd, dim3(BB * 64), dim3(256), 0, stream, zbuf, Ppart);
  hipLaunchKernelGGL(reduce_P, dim3((BB * LL) / 256), dim3(256), 0, stream, Ppart, Pbuf);
  hipLaunchKernelGGL(fft_inv_topk, dim3(BB), dim3(256), 0, stream, Pbuf, delays, probs);
  hipLaunchKernelGGL(agg_out, dim3((BB * LL * 64) / 256), dim3(256), 0, stream,
                     v, delays, probs, out);
}

// Round 10
// 112.862 us; speedup vs baseline: 2.1236x; 1.2185x over previous
//
#include <hip/hip_runtime.h>
#include <hip/hip_fp16.h>
#include <cstdint>
#include <cstddef>

#define BB 16
#define LL 2048
#define CC 512   // H*E
#define TK 7     // int(log(2048)) = 7
#define PDC(a) ((a) + ((a) >> 4))   // cf-unit LDS pad: +1 cf per 16
#define PSTR 1056                   // Ppart per-group stride (1025 used)

typedef float2 cf;
typedef __attribute__((ext_vector_type(4))) float f32x4v;

__device__ inline cf cadd(cf a, cf b){ return make_float2(a.x + b.x, a.y + b.y); }
__device__ inline cf csub(cf a, cf b){ return make_float2(a.x - b.x, a.y - b.y); }
__device__ inline cf cmul(cf a, cf b){ return make_float2(a.x*b.x - a.y*b.y, a.x*b.y + a.y*b.x); }

// S*i*z : forward S=-1 -> (z.y, -z.x); inverse S=+1 -> (-z.y, z.x)
template<int S> __device__ inline cf crot(cf z){
  return (S < 0) ? make_float2(z.y, -z.x) : make_float2(-z.y, z.x);
}

template<int S> __device__ inline void dft4(cf* x){
  const cf t0 = cadd(x[0], x[2]), t1 = csub(x[0], x[2]);
  const cf t2 = cadd(x[1], x[3]), t3 = csub(x[1], x[3]);
  const cf r = crot<S>(t3);
  x[0] = cadd(t0, t2); x[2] = csub(t0, t2);
  x[1] = cadd(t1, r);  x[3] = csub(t1, r);
}

template<int S> __device__ inline void dft8(cf* x){
  cf e[4] = { x[0], x[2], x[4], x[6] };
  cf o[4] = { x[1], x[3], x[5], x[7] };
  dft4<S>(e); dft4<S>(o);
  const float H = 0.70710678118654752440f;
  o[1] = cmul(o[1], make_float2(H, (float)S * H));
  o[2] = crot<S>(o[2]);
  o[3] = cmul(o[3], make_float2(-H, (float)S * H));
  x[0] = cadd(e[0], o[0]); x[4] = csub(e[0], o[0]);
  x[1] = cadd(e[1], o[1]); x[5] = csub(e[1], o[1]);
  x[2] = cadd(e[2], o[2]); x[6] = csub(e[2], o[2]);
  x[3] = cadd(e[3], o[3]); x[7] = csub(e[3], o[3]);
}

struct Tw { cf w2[7], w3[7], w4a[3], w4b[3]; };

template<int S>
__device__ inline void make_tw(int tid, Tw& T){
  const float base = (float)S * 6.283185307179586f / 2048.0f;
  const int j7 = tid & 7, j63 = tid & 63;
#pragma unroll
  for (int i = 0; i < 7; ++i){
    float s, c;
    __sincosf(base * (float)(32 * (i + 1) * j7), &s, &c);  T.w2[i] = make_float2(c, s);
    __sincosf(base * (float)( 4 * (i + 1) * j63), &s, &c); T.w3[i] = make_float2(c, s);
  }
#pragma unroll
  for (int i = 0; i < 3; ++i){
    float s, c;
    __sincosf(base * (float)((i + 1) * tid), &s, &c);         T.w4a[i] = make_float2(c, s);
    __sincosf(base * (float)((i + 1) * (tid + 256)), &s, &c); T.w4b[i] = make_float2(c, s);
  }
}

// Full 2048-pt Stockham FFT (radix 8-8-8-4), cf-interleaved LDS (b64 ops).
// Input: x[8] registers (x[t] = sample tid + 256t). Output: Z in Cc[PDC(f)].
// Leaves a trailing sync after stage-4 writes.
template<int S>
__device__ inline void fft2048(cf* x, cf* Bc, cf* Cc, const Tw& T, int tid){
  // stage 1: radix-8, Ls=1 (no twiddles)
  dft8<S>(x);
#pragma unroll
  for (int t = 0; t < 8; ++t) Bc[PDC((tid << 3) + t)] = x[t];
  __syncthreads();
  { // stage 2: radix-8, Ls=8
    cf y[8];
#pragma unroll
    for (int t = 0; t < 8; ++t) y[t] = Bc[PDC(tid + (t << 8))];
#pragma unroll
    for (int t = 1; t < 8; ++t) y[t] = cmul(y[t], T.w2[t - 1]);
    dft8<S>(y);
    const int base = ((tid >> 3) << 6) + (tid & 7);
#pragma unroll
    for (int t = 0; t < 8; ++t) Cc[PDC(base + (t << 3))] = y[t];
  }
  __syncthreads();
  { // stage 3: radix-8, Ls=64
    cf y[8];
#pragma unroll
    for (int t = 0; t < 8; ++t) y[t] = Cc[PDC(tid + (t << 8))];
#pragma unroll
    for (int t = 1; t < 8; ++t) y[t] = cmul(y[t], T.w3[t - 1]);
    dft8<S>(y);
    const int base = ((tid >> 6) << 9) + (tid & 63);
#pragma unroll
    for (int t = 0; t < 8; ++t) Bc[PDC(base + (t << 6))] = y[t];
  }
  __syncthreads();
  { // stage 4: radix-4, Ls=512 (two butterflies per thread)
#pragma unroll
    for (int h = 0; h < 2; ++h){
      const int j = tid + (h << 8);
      cf y[4];
#pragma unroll
      for (int t = 0; t < 4; ++t) y[t] = Bc[PDC(j + (t << 9))];
      const cf* w = h ? T.w4b : T.w4a;
#pragma unroll
      for (int t = 1; t < 4; ++t) y[t] = cmul(y[t], w[t - 1]);
      dft4<S>(y);
#pragma unroll
      for (int t = 0; t < 4; ++t) Cc[PDC(j + (t << 9))] = y[t];
    }
  }
  __syncthreads();
}

// ---------------------------------------------------------------------------
// Phase 1: z[b][c][t] = half2(q[b][t][c], k[b][t][c])  (64x64 fp16 LDS tile)
// q,k are single-use streams -> nontemporal loads (keep L3 for z/Ppart).
// ---------------------------------------------------------------------------
__global__ __launch_bounds__(256) void transpose_pack(const float* __restrict__ q,
                                                      const float* __restrict__ k,
                                                      __half2* __restrict__ z){
  int bid = blockIdx.x;
  const int tt = bid & 31; bid >>= 5;
  const int ct = bid & 7;  bid >>= 3;
  const int b = bid;
  const int t0 = tt << 6, c0 = ct << 6;
  __shared__ __half2 T[64][69];   // [t][c], pad 69 to break bank strides
  const int tid = threadIdx.x;
  const size_t inbase = ((size_t)b * LL + t0) * CC + c0;
  const int c4 = (tid & 15) << 2;
  f32x4v a[4], e[4];
#pragma unroll
  for (int p2 = 0; p2 < 4; ++p2){
    const int row = (p2 << 4) + (tid >> 4);
    a[p2] = __builtin_nontemporal_load(
        reinterpret_cast<const f32x4v*>(q + inbase + (size_t)row * CC + c4));
    e[p2] = __builtin_nontemporal_load(
        reinterpret_cast<const f32x4v*>(k + inbase + (size_t)row * CC + c4));
  }
#pragma unroll
  for (int p2 = 0; p2 < 4; ++p2){
    const int row = (p2 << 4) + (tid >> 4);
    T[row][c4 + 0] = __floats2half2_rn(a[p2][0], e[p2][0]);
    T[row][c4 + 1] = __floats2half2_rn(a[p2][1], e[p2][1]);
    T[row][c4 + 2] = __floats2half2_rn(a[p2][2], e[p2][2]);
    T[row][c4 + 3] = __floats2half2_rn(a[p2][3], e[p2][3]);
  }
  __syncthreads();
  const size_t outbase = ((size_t)b * CC + c0) * LL + (size_t)t0;
#pragma unroll
  for (int it = 0; it < 4; ++it){
    const int idx = (it << 8) + tid;
    const int c = idx >> 4;                 // c_local 0..63
    const int t4 = (idx & 15) << 2;         // t_local base (x4)
    const __half2 u0 = T[t4 + 0][c], u1 = T[t4 + 1][c];
    const __half2 u2 = T[t4 + 2][c], u3 = T[t4 + 3][c];
    uint4 w;
    w.x = *reinterpret_cast<const uint*>(&u0);
    w.y = *reinterpret_cast<const uint*>(&u1);
    w.z = *reinterpret_cast<const uint*>(&u2);
    w.w = *reinterpret_cast<const uint*>(&u3);
    *reinterpret_cast<uint4*>(&z[outbase + (size_t)c * LL + t4]) = w;
  }
}

// ---------------------------------------------------------------------------
// Phase 2: per (b, group of 8 channels): forward FFT of z_c = q_c + i*k_c,
// accumulate P[f] += Q_c[f]*conj(K_c[f]) for f in [0,1024] only (Hermitian:
// P[2048-f] = conj(P[f]), reconstructed in reduce_P).
// ---------------------------------------------------------------------------
__global__ __launch_bounds__(256) void fft_fwd(const __half2* __restrict__ z,
                                               float2* __restrict__ Ppart){
  int bid = blockIdx.x;
  const int g = bid & 63; const int b = bid >> 6;
  const int tid = threadIdx.x;
  __shared__ cf Bc[2176];
  __shared__ cf Cc[2176];
  Tw T; make_tw<-1>(tid, T);
  const __half2* zg = z + (((size_t)b * CC + (size_t)g * 8) << 11);
  float accRe[4] = {0,0,0,0};
  float accIm[4] = {0,0,0,0};
  float acc1024 = 0.f;
  __half2 h[8];
#pragma unroll
  for (int t = 0; t < 8; ++t) h[t] = zg[tid + (t << 8)];
  for (int ch = 0; ch < 8; ++ch){
    cf x[8];
#pragma unroll
    for (int t = 0; t < 8; ++t) x[t] = __half22float2(h[t]);
    if (ch < 7){
      const __half2* zn = zg + ((size_t)(ch + 1) << 11);
#pragma unroll
      for (int t = 0; t < 8; ++t) h[t] = zn[tid + (t << 8)];
    }
    fft2048<-1>(x, Bc, Cc, T, tid);
    // combine for f = tid + 256r, r<4 (covers 0..1023 exactly once):
    // Re(QconjK)[f] = 0.5*(Bi*Ar + Br*Ai), Im = 0.25*(|A|^2-|B|^2), B=Z[2048-f]
#pragma unroll
    for (int r = 0; r < 4; ++r){
      const int f = tid + (r << 8);
      const int p = (2048 - f) & 2047;
      const cf A = Cc[PDC(f)];
      const cf Bv = Cc[PDC(p)];
      accRe[r] += 0.5f  * (Bv.y * A.x + Bv.x * A.y);
      accIm[r] += 0.25f * (A.x * A.x + A.y * A.y - Bv.x * Bv.x - Bv.y * Bv.y);
    }
    if (tid == 0){
      const cf A = Cc[PDC(1024)];   // self-mirror: Re = Ar*Ai, Im = 0
      acc1024 += A.x * A.y;
    }
  }
  float2* pp = Ppart + ((size_t)b * 64 + g) * PSTR;
#pragma unroll
  for (int r = 0; r < 4; ++r)
    pp[tid + (r << 8)] = make_float2(accRe[r], accIm[r]);
  if (tid == 0) pp[1024] = make_float2(acc1024, 0.f);
}

// ---------------------------------------------------------------------------
// Phase 2b: P[b,f] = sum_g Ppart[b,g,min(f,2048-f)], conj for f>1024.
// ---------------------------------------------------------------------------
__global__ __launch_bounds__(256) void reduce_P(const float2* __restrict__ Ppart,
                                                float2* __restrict__ P){
  const int gid = blockIdx.x * 256 + threadIdx.x;  // 0..32767
  const int b = gid >> 11, f = gid & 2047;
  const int src = (f <= 1024) ? f : 2048 - f;
  const float sgn = (f <= 1024) ? 1.f : -1.f;
  float sr = 0.f, si = 0.f;
#pragma unroll 8
  for (int g = 0; g < 64; ++g){
    const float2 v = Ppart[((size_t)b * 64 + g) * PSTR + src];
    sr += v.x; si += v.y;
  }
  P[((size_t)b << 11) + f] = make_float2(sr, sgn * si);
}

// ---------------------------------------------------------------------------
// Phase 3: per b: inverse FFT of P, scale -> mv; fused top-7 + softmax.
// ---------------------------------------------------------------------------
__global__ __launch_bounds__(256) void fft_inv_topk(const float2* __restrict__ P,
                                                    int* __restrict__ delays,
                                                    float* __restrict__ probs){
  const int b = blockIdx.x;
  const int tid = threadIdx.x;
  __shared__ cf Bc[2176];
  __shared__ cf Cc[2176];
  __shared__ float vals[2048];
  __shared__ float rv[256]; __shared__ int ri[256];
  __shared__ float wsel[TK]; __shared__ int dsel[TK];
  Tw T; make_tw<1>(tid, T);
  cf x[8];
#pragma unroll
  for (int t = 0; t < 8; ++t) x[t] = P[((size_t)b << 11) + tid + (t << 8)];
  fft2048<1>(x, Bc, Cc, T, tid);
  const float scale = 1.0f / (2048.0f * 512.0f);
#pragma unroll
  for (int r = 0; r < 8; ++r){
    const int t = tid + (r << 8);
    vals[t] = Cc[PDC(t)].x * scale;
  }
  __syncthreads();
  for (int kk = 0; kk < TK; ++kk){
    float best = -1e30f; int bi = LL;
    for (int i = tid; i < LL; i += 256){
      const float xv = vals[i];
      if (xv > best){ best = xv; bi = i; }
    }
    rv[tid] = best; ri[tid] = bi;
    __syncthreads();
    for (int s = 128; s > 0; s >>= 1){
      if (tid < s){
        const float ov = rv[tid + s]; const int oi = ri[tid + s];
        if (ov > rv[tid] || (ov == rv[tid] && oi < ri[tid])){ rv[tid] = ov; ri[tid] = oi; }
      }
      __syncthreads();
    }
    if (tid == 0){ wsel[kk] = rv[0]; dsel[kk] = ri[0]; vals[ri[0]] = -1e30f; }
    __syncthreads();
  }
  if (tid == 0){
    const float m = wsel[0];
    float e[TK], ssum = 0.f;
#pragma unroll
    for (int i = 0; i < TK; ++i){ e[i] = expf(wsel[i] - m); ssum += e[i]; }
    const float inv = 1.0f / ssum;
#pragma unroll
    for (int i = 0; i < TK; ++i){
      probs[b * TK + i] = e[i] * inv;
      delays[b * TK + i] = dsel[i];
    }
  }
}

// ---------------------------------------------------------------------------
// Phase 4: out[b,t,:] = sum_k probs[b,k] * v[b,(t+delay[b,k])%L,:]
// XCD-aware swizzle: each XCD owns whole batches (v[b] = 4.2 MB ~ L2 size),
// so the 7 gather streams of a batch share one L2 -> v fetched ~once from HBM.
// 8192 blocks: xcd = bid&7, w = bid>>3; batch = 2*xcd + (w>>9); local = w&511.
// ---------------------------------------------------------------------------
__global__ __launch_bounds__(256) void agg_out(const float* __restrict__ v,
                                               const int* __restrict__ delays,
                                               const float* __restrict__ probs,
                                               float* __restrict__ out){
  const int bid = blockIdx.x;
  const int xcd = bid & 7;
  const int w = bid >> 3;
  const int b = (xcd << 1) + (w >> 9);
  const int local = w & 511;
  const int tid = threadIdx.x;
  const int t = (local << 2) + (tid >> 6);   // 4 rows per block
  const int i0 = tid & 63;                   // float4 slots i0 and i0+64
  const int row = (b << 11) + t;
  f32x4v acc0 = {0.f, 0.f, 0.f, 0.f};
  f32x4v acc1 = {0.f, 0.f, 0.f, 0.f};
#pragma unroll
  for (int kk = 0; kk < TK; ++kk){
    const int d = delays[b * TK + kk];
    const float p = probs[b * TK + kk];
    const int srcr = (t + d) & (LL - 1);
    const size_t base = (size_t)((b << 11) + srcr) * 128;
    const f32x4v x0 = reinterpret_cast<const f32x4v*>(v)[base + i0];
    const f32x4v x1 = reinterpret_cast<const f32x4v*>(v)[base + i0 + 64];
    acc0 += x0 * p;
    acc1 += x1 * p;
  }
  f32x4v* o = reinterpret_cast<f32x4v*>(out) + (size_t)row * 128;
  __builtin_nontemporal_store(acc0, o + i0);
  __builtin_nontemporal_store(acc1, o + i0 + 64);
}

// ---------------------------------------------------------------------------
extern "C" void kernel_launch(void* const* d_in, const int* in_sizes, int n_in,
                              void* d_out, int out_size, void* d_ws, size_t ws_size,
                              hipStream_t stream){
  const float* q = (const float*)d_in[0];
  const float* k = (const float*)d_in[1];
  const float* v = (const float*)d_in[2];
  float* out = (float*)d_out;

  char* ws = (char*)d_ws;
  const size_t Z_BYTES  = (size_t)BB * CC * LL * sizeof(__half2);   // 67.1 MB
  const size_t PP_BYTES = (size_t)BB * 64 * PSTR * sizeof(float2);  // 8.65 MB
  const size_t P_BYTES  = (size_t)BB * LL * sizeof(float2);         // 256 KB
  __half2* zbuf = (__half2*)ws;
  float2* Ppart = (float2*)(ws + Z_BYTES);
  float2* Pbuf  = (float2*)(ws + Z_BYTES + PP_BYTES);
  int* delays = (int*)(ws + Z_BYTES + PP_BYTES + P_BYTES);
  float* probs = (float*)(ws + Z_BYTES + PP_BYTES + P_BYTES + 1024);

  hipLaunchKernelGGL(transpose_pack, dim3(BB * 32 * 8), dim3(256), 0, stream, q, k, zbuf);
  hipLaunchKernelGGL(fft_fwd, dim3(BB * 64), dim3(256), 0, stream, zbuf, Ppart);
  hipLaunchKernelGGL(reduce_P, dim3((BB * LL) / 256), dim3(256), 0, stream, Ppart, Pbuf);
  hipLaunchKernelGGL(fft_inv_topk, dim3(BB), dim3(256), 0, stream, Pbuf, delays, probs);
  hipLaunchKernelGGL(agg_out, dim3(BB * 512), dim3(256), 0, stream,
                     v, delays, probs, out);
}